// Round 15
// baseline (1180.739 us; speedup 1.0000x reference)
//
#include <hip/hip_runtime.h>
#include <hip/hip_bf16.h>
#include <math.h>

typedef unsigned short u16;
typedef unsigned int u32;
typedef __bf16 bf16x8 __attribute__((ext_vector_type(8)));
typedef float f32x4 __attribute__((ext_vector_type(4)));

#define MROWS 100352   // 32 * 56 * 56
#define CDIM 512
#define SCALE_ATTN 0.17677669529663687f

__device__ __forceinline__ u16 f2bf(float f) {
    u32 u = __float_as_uint(f);
    u32 r = (u + 0x7fffu + ((u >> 16) & 1u)) >> 16;   // RNE
    return (u16)r;
}

__device__ __forceinline__ u32 cvtpk_bf16(float lo, float hi) {
    u32 r;
    asm volatile("v_cvt_pk_bf16_f32 %0, %1, %2" : "=v"(r) : "v"(lo), "v"(hi));
    return r;
}
__device__ __forceinline__ float fast_rcp(float x) {
    float r;
    asm volatile("v_rcp_f32 %0, %1" : "=v"(r) : "v"(x));
    return r;
}
__device__ __forceinline__ float fast_rsq(float x) {
    float r;
    asm volatile("v_rsq_f32 %0, %1" : "=v"(r) : "v"(x));
    return r;
}

// ---------------- transpose + cast: fp32 W[K][N] -> bf16 WT[N][K] ----------------
__global__ void transpose_cast(const float* __restrict__ W, u16* __restrict__ WT, int K, int N) {
    int idx = blockIdx.x * 256 + threadIdx.x;
    if (idx >= K * N) return;
    int k = idx / N, n = idx % N;
    WT[(size_t)n * K + k] = f2bf(W[idx]);
}

// ---------------- LayerNorm fp32 -> bf16, one wave per row (C=512) ----------------
__global__ __launch_bounds__(256) void ln_kernel(const float* __restrict__ x, const float* __restrict__ g,
                                                 const float* __restrict__ bta, u16* __restrict__ out) {
    int row = blockIdx.x * 4 + (threadIdx.x >> 6);
    int lane = threadIdx.x & 63;
    const float* xr = x + (size_t)row * CDIM + lane * 8;
    float4 v0 = *(const float4*)xr;
    float4 v1 = *(const float4*)(xr + 4);
    float xv[8] = {v0.x, v0.y, v0.z, v0.w, v1.x, v1.y, v1.z, v1.w};
    float s = 0.f, ss = 0.f;
#pragma unroll
    for (int i = 0; i < 8; ++i) { s += xv[i]; ss += xv[i] * xv[i]; }
#pragma unroll
    for (int o = 1; o < 64; o <<= 1) { s += __shfl_xor(s, o); ss += __shfl_xor(ss, o); }
    float mu = s * (1.f / CDIM);
    float var = ss * (1.f / CDIM) - mu * mu;
    float rs = fast_rsq(var + 1e-6f);
    int c = lane * 8;
    float y[8];
#pragma unroll
    for (int i = 0; i < 8; ++i)
        y[i] = (xv[i] - mu) * rs * g[c + i] + bta[c + i];
    uint4 ov;
    ov.x = cvtpk_bf16(y[0], y[1]);
    ov.y = cvtpk_bf16(y[2], y[3]);
    ov.z = cvtpk_bf16(y[4], y[5]);
    ov.w = cvtpk_bf16(y[6], y[7]);
    *(uint4*)(out + (size_t)row * CDIM + c) = ov;
}

#define BM 128
#define BN 128

enum { EPI_BF16 = 0, EPI_GELU_BF16 = 1, EPI_RES_F32 = 2 };

__device__ __forceinline__ void gload_lds16(const void* g, void* l) {
    __builtin_amdgcn_global_load_lds(
        (const __attribute__((address_space(1))) u32*)g,
        (__attribute__((address_space(3))) u32*)l, 16, 0, 0);
}

#define WAITVM4() asm volatile("s_waitcnt vmcnt(4)" ::: "memory")
#define WAITVM8() asm volatile("s_waitcnt vmcnt(8)" ::: "memory")
#define WAITVM12() asm volatile("s_waitcnt vmcnt(12)" ::: "memory")
#define WAITVM0() asm volatile("s_waitcnt vmcnt(0)" ::: "memory")
#define BARRIER() __builtin_amdgcn_s_barrier()
#define SCHEDBAR() __builtin_amdgcn_sched_barrier(0)

__device__ __forceinline__ float gelu_tanh(float x) {
    float y = x * fmaf(x * x, 0.0356774081f, 0.7978845608f);
    y = fmaxf(y, -15.f);
    float u = __expf(-2.f * y);
    float th = (1.f - u) * fast_rcp(1.f + u);
    return 0.5f * x * (1.f + th);
}

// ---------------- common epilogue (coalesced via per-wave LDS staging) ----------------
template <int EPI>
__device__ __forceinline__ void gemm_epilogue(f32x4 (&acc)[4][4], u16* smem,
                                              const float* __restrict__ bias, const float* __restrict__ res,
                                              void* __restrict__ outp, int N,
                                              int m0, int n0, int w, int lane) {
    const int r15 = lane & 15;
    float* ep = (float*)smem + w * (16 * 76);
    const int lg = lane >> 4;
#pragma unroll
    for (int mi = 0; mi < 4; ++mi) {
#pragma unroll
        for (int ni = 0; ni < 4; ++ni)
#pragma unroll
            for (int j = 0; j < 4; ++j)
                ep[(lg * 4 + j) * 76 + ni * 16 + r15] = acc[mi][ni][j];
#pragma unroll
        for (int p = 0; p < 4; ++p) {
            int lr = p * 4 + lg;
            f32x4 v = *(f32x4*)&ep[lr * 76 + r15 * 4];
            int grow = m0 + (w >> 1) * 64 + mi * 16 + lr;
            int gcol = n0 + (w & 1) * 64 + r15 * 4;
            float4 bv = *(const float4*)&bias[gcol];
            float o0 = v[0] + bv.x, o1 = v[1] + bv.y, o2 = v[2] + bv.z, o3 = v[3] + bv.w;
            if (EPI == EPI_GELU_BF16) {
                o0 = gelu_tanh(o0); o1 = gelu_tanh(o1); o2 = gelu_tanh(o2); o3 = gelu_tanh(o3);
            }
            if (EPI == EPI_RES_F32) {
                size_t off = (size_t)grow * N + gcol;
                float4 rv = *(const float4*)&res[off];
                float4 ov = make_float4(o0 + rv.x, o1 + rv.y, o2 + rv.z, o3 + rv.w);
                *(float4*)((float*)outp + off) = ov;
            } else {
                uint2 ov;
                ov.x = cvtpk_bf16(o0, o1);
                ov.y = cvtpk_bf16(o2, o3);
                *(uint2*)((u16*)outp + (size_t)grow * N + gcol) = ov;
            }
        }
    }
}

// ---------------- GEMM variant A: BK=32, 5 blocks/CU — for K=512 ----------------
// LDS 32KB x 5 = 160KB exact fit; VGPR 52 allows 8 waves/SIMD, so LDS is the cap.
#define BK32 32
#define BUFE32 (BM * BK32 + BN * BK32)   // 8192 u16 = 16KB

template <int EPI>
__global__ __launch_bounds__(256, 5) void gemm_bt32(const u16* __restrict__ A, const u16* __restrict__ BT,
                                                    const float* __restrict__ bias, const float* __restrict__ res,
                                                    void* __restrict__ outp, int M, int N, int K, int nnb) {
    __shared__ __align__(16) u16 smem[2 * BUFE32];   // 32 KB

    const int t = threadIdx.x;
    const int lane = t & 63;
    const int w = t >> 6;
    const int wr = w >> 1, wc = w & 1;

    const int nwg = gridDim.x;
    const int chunk = nwg >> 3;
    const int wg = (blockIdx.x & 7) * chunk + (blockIdx.x >> 3);
    const int m0 = (wg / nnb) * BM;
    const int n0 = (wg % nnb) * BN;

    f32x4 acc[4][4] = {};

    const int r15 = lane & 15;
    const int rc8 = (((lane >> 4) ^ ((r15 & 3) ^ ((r15 >> 2) & 3))) << 3);

    const int srow = t >> 2;                                        // 0..63
    const int scol = (((t & 3) ^ ((srow & 3) ^ ((srow >> 2) & 3))) << 3);
    const u16* Ag = A + (size_t)(m0 + srow) * K + scol;
    const u16* Bg = BT + (size_t)(n0 + srow) * K + scol;

    const int nt = K / BK32;

#define ISSUE32(buf_, tile_)                                                         \
    {                                                                                \
        u16* dst_ = smem + (buf_) * BUFE32;                                          \
        const int kt_ = (tile_) * BK32;                                              \
        _Pragma("unroll")                                                            \
        for (int i = 0; i < 2; ++i)                                                  \
            gload_lds16(Ag + (size_t)(i * 64) * K + kt_, &dst_[i * 2048 + t * 8]);   \
        _Pragma("unroll")                                                            \
        for (int i = 0; i < 2; ++i)                                                  \
            gload_lds16(Bg + (size_t)(i * 64) * K + kt_, &dst_[4096 + i * 2048 + t * 8]); \
    }

    ISSUE32(0, 0);
    ISSUE32(1, 1);

    for (int tt = 0; tt < nt; ++tt) {
        const int d = tt & 1;

        if (tt + 1 < nt) WAITVM4(); else WAITVM0();
        BARRIER();
        SCHEDBAR();

        const u16* As = smem + d * BUFE32;
        const u16* Bs = As + BM * BK32;
        bf16x8 af[4], bf[4];
#pragma unroll
        for (int mi = 0; mi < 4; ++mi)
            af[mi] = *(const bf16x8*)&As[(wr * 64 + mi * 16 + r15) * BK32 + rc8];
#pragma unroll
        for (int ni = 0; ni < 4; ++ni)
            bf[ni] = *(const bf16x8*)&Bs[(wc * 64 + ni * 16 + r15) * BK32 + rc8];
#pragma unroll
        for (int mi = 0; mi < 4; ++mi)
#pragma unroll
            for (int ni = 0; ni < 4; ++ni)
                acc[mi][ni] = __builtin_amdgcn_mfma_f32_16x16x32_bf16(af[mi], bf[ni], acc[mi][ni], 0, 0, 0);

        SCHEDBAR();
        BARRIER();
        if (tt + 2 < nt) ISSUE32(d, tt + 2);
    }
#undef ISSUE32

    gemm_epilogue<EPI>(acc, smem, bias, res, outp, N, m0, n0, w, lane);
}

// ---------------- GEMM variant B: BK=64, 2 blocks/CU — for K=2048 ----------------
#define BK64 64
#define BUFE64 (BM * BK64 + BN * BK64)   // 16384 u16 = 32KB

template <int EPI>
__global__ __launch_bounds__(256, 2) void gemm_bt64(const u16* __restrict__ A, const u16* __restrict__ BT,
                                                    const float* __restrict__ bias, const float* __restrict__ res,
                                                    void* __restrict__ outp, int M, int N, int K, int nnb) {
    __shared__ __align__(16) u16 smem[2 * BUFE64];   // 64 KB

    const int t = threadIdx.x;
    const int lane = t & 63;
    const int w = t >> 6;
    const int wr = w >> 1, wc = w & 1;

    const int nwg = gridDim.x;
    const int chunk = nwg >> 3;
    const int wg = (blockIdx.x & 7) * chunk + (blockIdx.x >> 3);
    const int m0 = (wg / nnb) * BM;
    const int n0 = (wg % nnb) * BN;

    f32x4 acc[4][4] = {};

    const int r15 = lane & 15;
    const int khalf = (lane >> 4) << 3;
    const int xorv = (r15 & 7) << 3;

    const int srow = t >> 3;
    const int scol = (((t & 7) ^ (srow & 7)) << 3);
    const u16* Ag = A + (size_t)(m0 + srow) * K + scol;
    const u16* Bg = BT + (size_t)(n0 + srow) * K + scol;

    const int nt = K / BK64;

#define ISSUE64(buf_, tile_)                                                         \
    {                                                                                \
        u16* dst_ = smem + (buf_) * BUFE64;                                          \
        const int kt_ = (tile_) * BK64;                                              \
        _Pragma("unroll")                                                            \
        for (int i = 0; i < 4; ++i)                                                  \
            gload_lds16(Ag + (size_t)(i * 32) * K + kt_, &dst_[i * 2048 + t * 8]);   \
        _Pragma("unroll")                                                            \
        for (int i = 0; i < 4; ++i)                                                  \
            gload_lds16(Bg + (size_t)(i * 32) * K + kt_, &dst_[8192 + i * 2048 + t * 8]); \
    }

    ISSUE64(0, 0);
    ISSUE64(1, 1);

    for (int tt = 0; tt < nt; ++tt) {
        const int d = tt & 1;

        if (tt + 1 < nt) WAITVM8(); else WAITVM0();
        BARRIER();
        SCHEDBAR();

        const u16* As = smem + d * BUFE64;
        const u16* Bs = As + BM * BK64;
        bf16x8 af[4][2], bf[4][2];
#pragma unroll
        for (int mi = 0; mi < 4; ++mi)
#pragma unroll
            for (int kk = 0; kk < 2; ++kk)
                af[mi][kk] = *(const bf16x8*)&As[(wr * 64 + mi * 16 + r15) * BK64 + ((kk * 32 + khalf) ^ xorv)];
#pragma unroll
        for (int ni = 0; ni < 4; ++ni)
#pragma unroll
            for (int kk = 0; kk < 2; ++kk)
                bf[ni][kk] = *(const bf16x8*)&Bs[(wc * 64 + ni * 16 + r15) * BK64 + ((kk * 32 + khalf) ^ xorv)];
#pragma unroll
        for (int kk = 0; kk < 2; ++kk)
#pragma unroll
            for (int mi = 0; mi < 4; ++mi)
#pragma unroll
                for (int ni = 0; ni < 4; ++ni)
                    acc[mi][ni] = __builtin_amdgcn_mfma_f32_16x16x32_bf16(af[mi][kk], bf[ni][kk], acc[mi][ni], 0, 0, 0);

        SCHEDBAR();
        BARRIER();
        if (tt + 2 < nt) ISSUE64(d, tt + 2);
    }
#undef ISSUE64

    gemm_epilogue<EPI>(acc, smem, bias, res, outp, N, m0, n0, w, lane);
}

// ---------------- windowed attention v3: MFMA, one block per window ----------------
__global__ __launch_bounds__(256) void attn_kernel(const u16* __restrict__ qkv, u16* __restrict__ aout) {
    __shared__ __align__(16) u16 smem[73728];   // 144 KB

    const int t = threadIdx.x;
    const int lane = t & 63;
    const int w = t >> 6;
    const int g = lane >> 4;
    const int r15 = lane & 15;
    const int wdw = blockIdx.x;
    const int b = wdw >> 6, wy = (wdw >> 3) & 7, wx = wdw & 7;
    const int base_row = b * 3136 + wy * 7 * 56 + wx * 7;

    const int WB = 32768 + w * 10240;

    const int sg_row = lane >> 2;
    const int sg_c = (lane & 3) ^ (sg_row & 3);
    int grq[4];
#pragma unroll
    for (int u = 0; u < 4; ++u) {
        int rr = u * 16 + sg_row; rr = rr > 48 ? 48 : rr;
        grq[u] = base_row + (rr / 7) * 56 + rr % 7;
    }
    const int r2v = lane & 31;
    const int dh = lane >> 5;
    int k0 = 2 * r2v, k1 = 2 * r2v + 1;
    k0 = k0 > 48 ? 48 : k0; k1 = k1 > 48 ? 48 : k1;
    const int grv0 = base_row + (k0 / 7) * 56 + k0 % 7;
    const int grv1 = base_row + (k1 / 7) * 56 + k1 % 7;

    const int fragsw = ((g ^ (r15 & 3)) << 3);

#define ATISSUE(rr_, bb_, va0_, va1_, vb0_, vb1_)                                    \
    {                                                                                \
        const int hh_ = w * 4 + (rr_);                                               \
        _Pragma("unroll")                                                            \
        for (int u = 0; u < 4; ++u)                                                  \
            gload_lds16(qkv + (size_t)grq[u] * 1536 + hh_ * 32 + sg_c * 8,           \
                        &smem[WB + (bb_) * 2048 + u * 512 + lane * 8]);              \
        _Pragma("unroll")                                                            \
        for (int u = 0; u < 4; ++u)                                                  \
            gload_lds16(qkv + (size_t)grq[u] * 1536 + 512 + hh_ * 32 + sg_c * 8,     \
                        &smem[WB + 4096 + (bb_) * 2048 + u * 512 + lane * 8]);       \
        const u16* vs0_ = qkv + (size_t)grv0 * 1536 + 1024 + hh_ * 32 + dh * 16;     \
        const u16* vs1_ = qkv + (size_t)grv1 * 1536 + 1024 + hh_ * 32 + dh * 16;     \
        va0_ = *(const uint4*)vs0_; va1_ = *(const uint4*)(vs0_ + 8);                \
        vb0_ = *(const uint4*)vs1_; vb1_ = *(const uint4*)(vs1_ + 8);                \
    }

    uint4 va0[2], va1[2], vb0[2], vb1[2];
    ATISSUE(0, 0, va0[0], va1[0], vb0[0], vb1[0]);

#pragma unroll
    for (int r = 0; r < 4; ++r) {
        const int bb = r & 1;
        const int hh = w * 4 + r;
        if (r < 3) ATISSUE(r + 1, bb ^ 1, va0[(r + 1) & 1], va1[(r + 1) & 1], vb0[(r + 1) & 1], vb1[(r + 1) & 1]);
        if (r < 3) WAITVM12(); else WAITVM0();
        SCHEDBAR();

        {
            u32 A[8], B[8];
            A[0] = va0[bb].x; A[1] = va0[bb].y; A[2] = va0[bb].z; A[3] = va0[bb].w;
            A[4] = va1[bb].x; A[5] = va1[bb].y; A[6] = va1[bb].z; A[7] = va1[bb].w;
            B[0] = vb0[bb].x; B[1] = vb0[bb].y; B[2] = vb0[bb].z; B[3] = vb0[bb].w;
            B[4] = vb1[bb].x; B[5] = vb1[bb].y; B[6] = vb1[bb].z; B[7] = vb1[bb].w;
#pragma unroll
            for (int i = 0; i < 16; ++i) {
                u32 a16 = (A[i >> 1] >> (16 * (i & 1))) & 0xffffu;
                u32 b16 = (B[i >> 1] >> (16 * (i & 1))) & 0xffffu;
                u32 val = a16 | (b16 << 16);
                int d = dh * 16 + i;
                int cph = (r2v >> 2) ^ (d & 7);
                ((u32*)smem)[(WB + 8192 + d * 64 + cph * 8 + 2 * (r2v & 3)) >> 1] = val;
            }
        }

        const int QB = WB + bb * 2048;
        const int KB = WB + 4096 + bb * 2048;
        f32x4 s[4][4] = {};
        {
            bf16x8 kf[4], qf[4];
#pragma unroll
            for (int mi = 0; mi < 4; ++mi)
                kf[mi] = *(const bf16x8*)&smem[KB + (16 * mi + r15) * 32 + fragsw];
#pragma unroll
            for (int ni = 0; ni < 4; ++ni)
                qf[ni] = *(const bf16x8*)&smem[QB + (16 * ni + r15) * 32 + fragsw];
#pragma unroll
            for (int mi = 0; mi < 4; ++mi)
#pragma unroll
                for (int ni = 0; ni < 4; ++ni)
                    s[mi][ni] = __builtin_amdgcn_mfma_f32_16x16x32_bf16(kf[mi], qf[ni], s[mi][ni], 0, 0, 0);
        }

        float inv4[4];
#pragma unroll
        for (int ni = 0; ni < 4; ++ni) {
            float mx = -1e30f;
#pragma unroll
            for (int mi = 0; mi < 4; ++mi)
#pragma unroll
                for (int jj = 0; jj < 4; ++jj) {
                    float v = s[mi][ni][jj] * SCALE_ATTN;
                    if (mi == 3 && !(g == 0 && jj == 0)) v = -1e30f;
                    s[mi][ni][jj] = v;
                    mx = fmaxf(mx, v);
                }
            mx = fmaxf(mx, __shfl_xor(mx, 16));
            mx = fmaxf(mx, __shfl_xor(mx, 32));
            float sum = 0.f;
#pragma unroll
            for (int mi = 0; mi < 4; ++mi)
#pragma unroll
                for (int jj = 0; jj < 4; ++jj) {
                    float e = __expf(s[mi][ni][jj] - mx);
                    s[mi][ni][jj] = e;
                    sum += e;
                }
            sum += __shfl_xor(sum, 16);
            sum += __shfl_xor(sum, 32);
            inv4[ni] = fast_rcp(sum);
        }

        f32x4 o[4][2] = {};
#pragma unroll
        for (int kh = 0; kh < 2; ++kh) {
#pragma unroll
            for (int m1 = 0; m1 < 2; ++m1) {
                const int mi = 2 * kh + m1;
#pragma unroll
                for (int ni = 0; ni < 4; ++ni)
#pragma unroll
                    for (int jp = 0; jp < 2; ++jp) {
                        float p0 = s[mi][ni][2 * jp] * inv4[ni];
                        float p1 = s[mi][ni][2 * jp + 1] * inv4[ni];
                        u32 val = cvtpk_bf16(p0, p1);
                        int q = 16 * ni + r15;
                        int cph = (2 * m1 + (g >> 1)) ^ (r15 & 3);
                        int off = 4 * (g & 1) + 2 * jp;
                        ((u32*)smem)[(QB + q * 32 + cph * 8 + off) >> 1] = val;
                    }
            }
            bf16x8 pf[4], vf[2];
#pragma unroll
            for (int mi = 0; mi < 4; ++mi)
                pf[mi] = *(const bf16x8*)&smem[QB + (16 * mi + r15) * 32 + fragsw];
#pragma unroll
            for (int ni = 0; ni < 2; ++ni)
                vf[ni] = *(const bf16x8*)&smem[WB + 8192 + (16 * ni + r15) * 64 + ((((4 * kh + g) ^ (r15 & 7))) << 3)];
#pragma unroll
            for (int mi = 0; mi < 4; ++mi)
#pragma unroll
                for (int ni = 0; ni < 2; ++ni)
                    o[mi][ni] = __builtin_amdgcn_mfma_f32_16x16x32_bf16(pf[mi], vf[ni], o[mi][ni], 0, 0, 0);
        }

#pragma unroll
        for (int mi = 0; mi < 4; ++mi)
#pragma unroll
            for (int ni = 0; ni < 2; ++ni)
#pragma unroll
                for (int jj = 0; jj < 4; ++jj) {
                    float ov = o[mi][ni][jj];
                    float op = __shfl_xor(ov, 1);
                    int q = 16 * mi + 4 * g + jj;
                    bool valid = (mi < 3) || (g == 0 && jj == 0);
                    if (((lane & 1) == 0) && valid) {
                        int col = hh * 32 + 16 * ni + r15;
                        int chv = ((col >> 3) ^ ((q >> 2) & 7));
                        ((u32*)smem)[(q * 512 + chv * 8 + (col & 7)) >> 1] = cvtpk_bf16(ov, op);
                    }
                }
    }
#undef ATISSUE

    __syncthreads();
    for (int c = t; c < 3136; c += 256) {
        int r = c >> 6, j = c & 63;
        int chv = j ^ ((r >> 2) & 7);
        uint4 v = *(const uint4*)&smem[r * 512 + chv * 8];
        int gr = base_row + (r / 7) * 56 + r % 7;
        *(uint4*)(aout + (size_t)gr * 512 + j * 8) = v;
    }
}

// ---------------- launch ----------------
extern "C" void kernel_launch(void* const* d_in, const int* in_sizes, int n_in,
                              void* d_out, int out_size, void* d_ws, size_t ws_size,
                              hipStream_t stream) {
    (void)in_sizes; (void)n_in; (void)out_size; (void)ws_size;
    const float* x      = (const float*)d_in[0];
    const float* ln1_g  = (const float*)d_in[1];
    const float* ln1_b  = (const float*)d_in[2];
    const float* qkv_w  = (const float*)d_in[3];
    const float* qkv_b  = (const float*)d_in[4];
    const float* proj_w = (const float*)d_in[5];
    const float* proj_b = (const float*)d_in[6];
    const float* ln2_g  = (const float*)d_in[7];
    const float* ln2_b  = (const float*)d_in[8];
    const float* mlp_w1 = (const float*)d_in[9];
    const float* mlp_b1 = (const float*)d_in[10];
    const float* mlp_w2 = (const float*)d_in[11];
    const float* mlp_b2 = (const float*)d_in[12];
    float* out = (float*)d_out;

    const int M = MROWS;
    char* ws = (char*)d_ws;
    const size_t SZ_H   = (size_t)M * 512 * 2;
    const size_t SZ_X2  = (size_t)M * 512 * 4;
    const size_t SZ_BIG = (size_t)M * 2048 * 2;
    u16*   h    = (u16*)ws;
    float* x2   = (float*)(ws + SZ_H);
    u16*   big  = (u16*)(ws + SZ_H + SZ_X2);
    u16*   qkv_wT  = (u16*)(ws + SZ_H + SZ_X2 + SZ_BIG);
    u16*   proj_wT = qkv_wT + 1536 * 512;
    u16*   w1T     = proj_wT + 512 * 512;
    u16*   w2T     = w1T + 2048 * 512;

    transpose_cast<<<(512 * 1536 + 255) / 256, 256, 0, stream>>>(qkv_w, qkv_wT, 512, 1536);
    transpose_cast<<<(512 * 512 + 255) / 256, 256, 0, stream>>>(proj_w, proj_wT, 512, 512);
    transpose_cast<<<(512 * 2048 + 255) / 256, 256, 0, stream>>>(mlp_w1, w1T, 512, 2048);
    transpose_cast<<<(2048 * 512 + 255) / 256, 256, 0, stream>>>(mlp_w2, w2T, 2048, 512);

    ln_kernel<<<M / 4, 256, 0, stream>>>(x, ln1_g, ln1_b, h);

    // K=512 GEMMs: BK=32 / 5 blocks/CU
    gemm_bt32<EPI_BF16><<<(M / BM) * (1536 / BN), 256, 0, stream>>>(h, qkv_wT, qkv_b, nullptr, big, M, 1536, 512, 1536 / BN);

    attn_kernel<<<2048, 256, 0, stream>>>(big, h);

    gemm_bt32<EPI_RES_F32><<<(M / BM) * (512 / BN), 256, 0, stream>>>(h, proj_wT, proj_b, x, x2, M, 512, 512, 512 / BN);

    ln_kernel<<<M / 4, 256, 0, stream>>>(x2, ln2_g, ln2_b, h);

    gemm_bt32<EPI_GELU_BF16><<<(M / BM) * (2048 / BN), 256, 0, stream>>>(h, w1T, mlp_b1, nullptr, big, M, 2048, 512, 2048 / BN);

    // K=2048 GEMM: BK=64 / 2 blocks/CU
    gemm_bt64<EPI_RES_F32><<<(M / BM) * (512 / BN), 256, 0, stream>>>(big, w2T, mlp_b2, x2, out, M, 512, 2048, 512 / BN);
}

// Round 16
// 1150.456 us; speedup vs baseline: 1.0263x; 1.0263x over previous
//
#include <hip/hip_runtime.h>
#include <hip/hip_bf16.h>
#include <math.h>

typedef unsigned short u16;
typedef unsigned int u32;
typedef __bf16 bf16x8 __attribute__((ext_vector_type(8)));
typedef float f32x4 __attribute__((ext_vector_type(4)));

#define MROWS 100352   // 32 * 56 * 56
#define CDIM 512
#define SCALE_ATTN 0.17677669529663687f

__device__ __forceinline__ u16 f2bf(float f) {
    u32 u = __float_as_uint(f);
    u32 r = (u + 0x7fffu + ((u >> 16) & 1u)) >> 16;   // RNE
    return (u16)r;
}
__device__ __forceinline__ float bf2f(u16 h) {
    return __uint_as_float(((u32)h) << 16);
}

__device__ __forceinline__ u32 cvtpk_bf16(float lo, float hi) {
    u32 r;
    asm volatile("v_cvt_pk_bf16_f32 %0, %1, %2" : "=v"(r) : "v"(lo), "v"(hi));
    return r;
}
__device__ __forceinline__ float fast_rcp(float x) {
    float r;
    asm volatile("v_rcp_f32 %0, %1" : "=v"(r) : "v"(x));
    return r;
}
__device__ __forceinline__ float fast_rsq(float x) {
    float r;
    asm volatile("v_rsq_f32 %0, %1" : "=v"(r) : "v"(x));
    return r;
}

// ---------------- transpose + cast: fp32 W[K][N] -> bf16 WT[N][K] ----------------
__global__ void transpose_cast(const float* __restrict__ W, u16* __restrict__ WT, int K, int N) {
    int idx = blockIdx.x * 256 + threadIdx.x;
    if (idx >= K * N) return;
    int k = idx / N, n = idx % N;
    WT[(size_t)n * K + k] = f2bf(W[idx]);
}

// ---------------- LayerNorm fp32-in -> bf16, one wave per row (C=512) ----------------
__global__ __launch_bounds__(256) void ln_kernel(const float* __restrict__ x, const float* __restrict__ g,
                                                 const float* __restrict__ bta, u16* __restrict__ out) {
    int row = blockIdx.x * 4 + (threadIdx.x >> 6);
    int lane = threadIdx.x & 63;
    const float* xr = x + (size_t)row * CDIM + lane * 8;
    float4 v0 = *(const float4*)xr;
    float4 v1 = *(const float4*)(xr + 4);
    float xv[8] = {v0.x, v0.y, v0.z, v0.w, v1.x, v1.y, v1.z, v1.w};
    float s = 0.f, ss = 0.f;
#pragma unroll
    for (int i = 0; i < 8; ++i) { s += xv[i]; ss += xv[i] * xv[i]; }
#pragma unroll
    for (int o = 1; o < 64; o <<= 1) { s += __shfl_xor(s, o); ss += __shfl_xor(ss, o); }
    float mu = s * (1.f / CDIM);
    float var = ss * (1.f / CDIM) - mu * mu;
    float rs = fast_rsq(var + 1e-6f);
    int c = lane * 8;
    float y[8];
#pragma unroll
    for (int i = 0; i < 8; ++i)
        y[i] = (xv[i] - mu) * rs * g[c + i] + bta[c + i];
    uint4 ov;
    ov.x = cvtpk_bf16(y[0], y[1]);
    ov.y = cvtpk_bf16(y[2], y[3]);
    ov.z = cvtpk_bf16(y[4], y[5]);
    ov.w = cvtpk_bf16(y[6], y[7]);
    *(uint4*)(out + (size_t)row * CDIM + c) = ov;
}

// ---------------- LayerNorm bf16-in -> bf16 (for x2 stored as bf16) ----------------
__global__ __launch_bounds__(256) void ln_kernel_bf16(const u16* __restrict__ x, const float* __restrict__ g,
                                                      const float* __restrict__ bta, u16* __restrict__ out) {
    int row = blockIdx.x * 4 + (threadIdx.x >> 6);
    int lane = threadIdx.x & 63;
    const u16* xr = x + (size_t)row * CDIM + lane * 8;
    uint4 v = *(const uint4*)xr;
    float xv[8];
    xv[0] = __uint_as_float(v.x << 16); xv[1] = __uint_as_float(v.x & 0xffff0000u);
    xv[2] = __uint_as_float(v.y << 16); xv[3] = __uint_as_float(v.y & 0xffff0000u);
    xv[4] = __uint_as_float(v.z << 16); xv[5] = __uint_as_float(v.z & 0xffff0000u);
    xv[6] = __uint_as_float(v.w << 16); xv[7] = __uint_as_float(v.w & 0xffff0000u);
    float s = 0.f, ss = 0.f;
#pragma unroll
    for (int i = 0; i < 8; ++i) { s += xv[i]; ss += xv[i] * xv[i]; }
#pragma unroll
    for (int o = 1; o < 64; o <<= 1) { s += __shfl_xor(s, o); ss += __shfl_xor(ss, o); }
    float mu = s * (1.f / CDIM);
    float var = ss * (1.f / CDIM) - mu * mu;
    float rs = fast_rsq(var + 1e-6f);
    int c = lane * 8;
    float y[8];
#pragma unroll
    for (int i = 0; i < 8; ++i)
        y[i] = (xv[i] - mu) * rs * g[c + i] + bta[c + i];
    uint4 ov;
    ov.x = cvtpk_bf16(y[0], y[1]);
    ov.y = cvtpk_bf16(y[2], y[3]);
    ov.z = cvtpk_bf16(y[4], y[5]);
    ov.w = cvtpk_bf16(y[6], y[7]);
    *(uint4*)(out + (size_t)row * CDIM + c) = ov;
}

#define BM 128
#define BN 128

enum { EPI_BF16 = 0, EPI_GELU_BF16 = 1, EPI_RES_BF16 = 2, EPI_RESBF_F32 = 3 };

__device__ __forceinline__ void gload_lds16(const void* g, void* l) {
    __builtin_amdgcn_global_load_lds(
        (const __attribute__((address_space(1))) u32*)g,
        (__attribute__((address_space(3))) u32*)l, 16, 0, 0);
}

#define WAITVM4() asm volatile("s_waitcnt vmcnt(4)" ::: "memory")
#define WAITVM8() asm volatile("s_waitcnt vmcnt(8)" ::: "memory")
#define WAITVM12() asm volatile("s_waitcnt vmcnt(12)" ::: "memory")
#define WAITVM0() asm volatile("s_waitcnt vmcnt(0)" ::: "memory")
#define BARRIER() __builtin_amdgcn_s_barrier()
#define SCHEDBAR() __builtin_amdgcn_sched_barrier(0)

__device__ __forceinline__ float gelu_tanh(float x) {
    float y = x * fmaf(x * x, 0.0356774081f, 0.7978845608f);
    y = fmaxf(y, -15.f);
    float u = __expf(-2.f * y);
    float th = (1.f - u) * fast_rcp(1.f + u);
    return 0.5f * x * (1.f + th);
}

// ---------------- common epilogue (coalesced via per-wave LDS staging) ----------------
// EPI_BF16:      out bf16 = v + bias
// EPI_GELU_BF16: out bf16 = gelu(v + bias)
// EPI_RES_BF16:  out bf16 = v + bias + res_fp32      (proj -> x2 stored bf16)
// EPI_RESBF_F32: out fp32 = v + bias + res_bf16      (mlp2 -> final out)
template <int EPI>
__device__ __forceinline__ void gemm_epilogue(f32x4 (&acc)[4][4], u16* smem,
                                              const float* __restrict__ bias, const void* __restrict__ res,
                                              void* __restrict__ outp, int N,
                                              int m0, int n0, int w, int lane) {
    const int r15 = lane & 15;
    float* ep = (float*)smem + w * (16 * 76);
    const int lg = lane >> 4;
#pragma unroll
    for (int mi = 0; mi < 4; ++mi) {
#pragma unroll
        for (int ni = 0; ni < 4; ++ni)
#pragma unroll
            for (int j = 0; j < 4; ++j)
                ep[(lg * 4 + j) * 76 + ni * 16 + r15] = acc[mi][ni][j];
#pragma unroll
        for (int p = 0; p < 4; ++p) {
            int lr = p * 4 + lg;
            f32x4 v = *(f32x4*)&ep[lr * 76 + r15 * 4];
            int grow = m0 + (w >> 1) * 64 + mi * 16 + lr;
            int gcol = n0 + (w & 1) * 64 + r15 * 4;
            float4 bv = *(const float4*)&bias[gcol];
            float o0 = v[0] + bv.x, o1 = v[1] + bv.y, o2 = v[2] + bv.z, o3 = v[3] + bv.w;
            size_t off = (size_t)grow * N + gcol;
            if (EPI == EPI_GELU_BF16) {
                o0 = gelu_tanh(o0); o1 = gelu_tanh(o1); o2 = gelu_tanh(o2); o3 = gelu_tanh(o3);
            }
            if (EPI == EPI_RES_BF16) {
                float4 rv = *(const float4*)((const float*)res + off);
                o0 += rv.x; o1 += rv.y; o2 += rv.z; o3 += rv.w;
            }
            if (EPI == EPI_RESBF_F32) {
                uint2 rb = *(const uint2*)((const u16*)res + off);
                o0 += __uint_as_float(rb.x << 16);
                o1 += __uint_as_float(rb.x & 0xffff0000u);
                o2 += __uint_as_float(rb.y << 16);
                o3 += __uint_as_float(rb.y & 0xffff0000u);
                float4 ov = make_float4(o0, o1, o2, o3);
                *(float4*)((float*)outp + off) = ov;
            } else {
                uint2 ov;
                ov.x = cvtpk_bf16(o0, o1);
                ov.y = cvtpk_bf16(o2, o3);
                *(uint2*)((u16*)outp + off) = ov;
            }
        }
    }
}

// ---------------- GEMM variant A: BK=32, 4 blocks/CU — for K=512 ----------------
#define BK32 32
#define BUFE32 (BM * BK32 + BN * BK32)   // 8192 u16 = 16KB

template <int EPI>
__global__ __launch_bounds__(256, 4) void gemm_bt32(const u16* __restrict__ A, const u16* __restrict__ BT,
                                                    const float* __restrict__ bias, const void* __restrict__ res,
                                                    void* __restrict__ outp, int M, int N, int K, int nnb) {
    __shared__ __align__(16) u16 smem[2 * BUFE32];   // 32 KB

    const int t = threadIdx.x;
    const int lane = t & 63;
    const int w = t >> 6;
    const int wr = w >> 1, wc = w & 1;

    const int nwg = gridDim.x;
    const int chunk = nwg >> 3;
    const int wg = (blockIdx.x & 7) * chunk + (blockIdx.x >> 3);
    const int m0 = (wg / nnb) * BM;
    const int n0 = (wg % nnb) * BN;

    f32x4 acc[4][4] = {};

    const int r15 = lane & 15;
    const int rc8 = (((lane >> 4) ^ ((r15 & 3) ^ ((r15 >> 2) & 3))) << 3);

    const int srow = t >> 2;                                        // 0..63
    const int scol = (((t & 3) ^ ((srow & 3) ^ ((srow >> 2) & 3))) << 3);
    const u16* Ag = A + (size_t)(m0 + srow) * K + scol;
    const u16* Bg = BT + (size_t)(n0 + srow) * K + scol;

    const int nt = K / BK32;

#define ISSUE32(buf_, tile_)                                                         \
    {                                                                                \
        u16* dst_ = smem + (buf_) * BUFE32;                                          \
        const int kt_ = (tile_) * BK32;                                              \
        _Pragma("unroll")                                                            \
        for (int i = 0; i < 2; ++i)                                                  \
            gload_lds16(Ag + (size_t)(i * 64) * K + kt_, &dst_[i * 2048 + t * 8]);   \
        _Pragma("unroll")                                                            \
        for (int i = 0; i < 2; ++i)                                                  \
            gload_lds16(Bg + (size_t)(i * 64) * K + kt_, &dst_[4096 + i * 2048 + t * 8]); \
    }

    ISSUE32(0, 0);
    ISSUE32(1, 1);

    for (int tt = 0; tt < nt; ++tt) {
        const int d = tt & 1;

        if (tt + 1 < nt) WAITVM4(); else WAITVM0();
        BARRIER();
        SCHEDBAR();

        const u16* As = smem + d * BUFE32;
        const u16* Bs = As + BM * BK32;
        bf16x8 af[4], bf[4];
#pragma unroll
        for (int mi = 0; mi < 4; ++mi)
            af[mi] = *(const bf16x8*)&As[(wr * 64 + mi * 16 + r15) * BK32 + rc8];
#pragma unroll
        for (int ni = 0; ni < 4; ++ni)
            bf[ni] = *(const bf16x8*)&Bs[(wc * 64 + ni * 16 + r15) * BK32 + rc8];
#pragma unroll
        for (int mi = 0; mi < 4; ++mi)
#pragma unroll
            for (int ni = 0; ni < 4; ++ni)
                acc[mi][ni] = __builtin_amdgcn_mfma_f32_16x16x32_bf16(af[mi], bf[ni], acc[mi][ni], 0, 0, 0);

        SCHEDBAR();
        BARRIER();
        if (tt + 2 < nt) ISSUE32(d, tt + 2);
    }
#undef ISSUE32

    gemm_epilogue<EPI>(acc, smem, bias, res, outp, N, m0, n0, w, lane);
}

// ---------------- GEMM variant B: BK=64, 2 blocks/CU — for K=2048 ----------------
#define BK64 64
#define BUFE64 (BM * BK64 + BN * BK64)   // 16384 u16 = 32KB

template <int EPI>
__global__ __launch_bounds__(256, 2) void gemm_bt64(const u16* __restrict__ A, const u16* __restrict__ BT,
                                                    const float* __restrict__ bias, const void* __restrict__ res,
                                                    void* __restrict__ outp, int M, int N, int K, int nnb) {
    __shared__ __align__(16) u16 smem[2 * BUFE64];   // 64 KB

    const int t = threadIdx.x;
    const int lane = t & 63;
    const int w = t >> 6;
    const int wr = w >> 1, wc = w & 1;

    const int nwg = gridDim.x;
    const int chunk = nwg >> 3;
    const int wg = (blockIdx.x & 7) * chunk + (blockIdx.x >> 3);
    const int m0 = (wg / nnb) * BM;
    const int n0 = (wg % nnb) * BN;

    f32x4 acc[4][4] = {};

    const int r15 = lane & 15;
    const int khalf = (lane >> 4) << 3;
    const int xorv = (r15 & 7) << 3;

    const int srow = t >> 3;
    const int scol = (((t & 7) ^ (srow & 7)) << 3);
    const u16* Ag = A + (size_t)(m0 + srow) * K + scol;
    const u16* Bg = BT + (size_t)(n0 + srow) * K + scol;

    const int nt = K / BK64;

#define ISSUE64(buf_, tile_)                                                         \
    {                                                                                \
        u16* dst_ = smem + (buf_) * BUFE64;                                          \
        const int kt_ = (tile_) * BK64;                                              \
        _Pragma("unroll")                                                            \
        for (int i = 0; i < 4; ++i)                                                  \
            gload_lds16(Ag + (size_t)(i * 32) * K + kt_, &dst_[i * 2048 + t * 8]);   \
        _Pragma("unroll")                                                            \
        for (int i = 0; i < 4; ++i)                                                  \
            gload_lds16(Bg + (size_t)(i * 32) * K + kt_, &dst_[8192 + i * 2048 + t * 8]); \
    }

    ISSUE64(0, 0);
    ISSUE64(1, 1);

    for (int tt = 0; tt < nt; ++tt) {
        const int d = tt & 1;

        if (tt + 1 < nt) WAITVM8(); else WAITVM0();
        BARRIER();
        SCHEDBAR();

        const u16* As = smem + d * BUFE64;
        const u16* Bs = As + BM * BK64;
        bf16x8 af[4][2], bf[4][2];
#pragma unroll
        for (int mi = 0; mi < 4; ++mi)
#pragma unroll
            for (int kk = 0; kk < 2; ++kk)
                af[mi][kk] = *(const bf16x8*)&As[(wr * 64 + mi * 16 + r15) * BK64 + ((kk * 32 + khalf) ^ xorv)];
#pragma unroll
        for (int ni = 0; ni < 4; ++ni)
#pragma unroll
            for (int kk = 0; kk < 2; ++kk)
                bf[ni][kk] = *(const bf16x8*)&Bs[(wc * 64 + ni * 16 + r15) * BK64 + ((kk * 32 + khalf) ^ xorv)];
#pragma unroll
        for (int kk = 0; kk < 2; ++kk)
#pragma unroll
            for (int mi = 0; mi < 4; ++mi)
#pragma unroll
                for (int ni = 0; ni < 4; ++ni)
                    acc[mi][ni] = __builtin_amdgcn_mfma_f32_16x16x32_bf16(af[mi][kk], bf[ni][kk], acc[mi][ni], 0, 0, 0);

        SCHEDBAR();
        BARRIER();
        if (tt + 2 < nt) ISSUE64(d, tt + 2);
    }
#undef ISSUE64

    gemm_epilogue<EPI>(acc, smem, bias, res, outp, N, m0, n0, w, lane);
}

// ---------------- windowed attention v3: MFMA, one block per window ----------------
__global__ __launch_bounds__(256) void attn_kernel(const u16* __restrict__ qkv, u16* __restrict__ aout) {
    __shared__ __align__(16) u16 smem[73728];   // 144 KB

    const int t = threadIdx.x;
    const int lane = t & 63;
    const int w = t >> 6;
    const int g = lane >> 4;
    const int r15 = lane & 15;
    const int wdw = blockIdx.x;
    const int b = wdw >> 6, wy = (wdw >> 3) & 7, wx = wdw & 7;
    const int base_row = b * 3136 + wy * 7 * 56 + wx * 7;

    const int WB = 32768 + w * 10240;

    const int sg_row = lane >> 2;
    const int sg_c = (lane & 3) ^ (sg_row & 3);
    int grq[4];
#pragma unroll
    for (int u = 0; u < 4; ++u) {
        int rr = u * 16 + sg_row; rr = rr > 48 ? 48 : rr;
        grq[u] = base_row + (rr / 7) * 56 + rr % 7;
    }
    const int r2v = lane & 31;
    const int dh = lane >> 5;
    int k0 = 2 * r2v, k1 = 2 * r2v + 1;
    k0 = k0 > 48 ? 48 : k0; k1 = k1 > 48 ? 48 : k1;
    const int grv0 = base_row + (k0 / 7) * 56 + k0 % 7;
    const int grv1 = base_row + (k1 / 7) * 56 + k1 % 7;

    const int fragsw = ((g ^ (r15 & 3)) << 3);

#define ATISSUE(rr_, bb_, va0_, va1_, vb0_, vb1_)                                    \
    {                                                                                \
        const int hh_ = w * 4 + (rr_);                                               \
        _Pragma("unroll")                                                            \
        for (int u = 0; u < 4; ++u)                                                  \
            gload_lds16(qkv + (size_t)grq[u] * 1536 + hh_ * 32 + sg_c * 8,           \
                        &smem[WB + (bb_) * 2048 + u * 512 + lane * 8]);              \
        _Pragma("unroll")                                                            \
        for (int u = 0; u < 4; ++u)                                                  \
            gload_lds16(qkv + (size_t)grq[u] * 1536 + 512 + hh_ * 32 + sg_c * 8,     \
                        &smem[WB + 4096 + (bb_) * 2048 + u * 512 + lane * 8]);       \
        const u16* vs0_ = qkv + (size_t)grv0 * 1536 + 1024 + hh_ * 32 + dh * 16;     \
        const u16* vs1_ = qkv + (size_t)grv1 * 1536 + 1024 + hh_ * 32 + dh * 16;     \
        va0_ = *(const uint4*)vs0_; va1_ = *(const uint4*)(vs0_ + 8);                \
        vb0_ = *(const uint4*)vs1_; vb1_ = *(const uint4*)(vs1_ + 8);                \
    }

    uint4 va0[2], va1[2], vb0[2], vb1[2];
    ATISSUE(0, 0, va0[0], va1[0], vb0[0], vb1[0]);

#pragma unroll
    for (int r = 0; r < 4; ++r) {
        const int bb = r & 1;
        const int hh = w * 4 + r;
        if (r < 3) ATISSUE(r + 1, bb ^ 1, va0[(r + 1) & 1], va1[(r + 1) & 1], vb0[(r + 1) & 1], vb1[(r + 1) & 1]);
        if (r < 3) WAITVM12(); else WAITVM0();
        SCHEDBAR();

        {
            u32 A[8], B[8];
            A[0] = va0[bb].x; A[1] = va0[bb].y; A[2] = va0[bb].z; A[3] = va0[bb].w;
            A[4] = va1[bb].x; A[5] = va1[bb].y; A[6] = va1[bb].z; A[7] = va1[bb].w;
            B[0] = vb0[bb].x; B[1] = vb0[bb].y; B[2] = vb0[bb].z; B[3] = vb0[bb].w;
            B[4] = vb1[bb].x; B[5] = vb1[bb].y; B[6] = vb1[bb].z; B[7] = vb1[bb].w;
#pragma unroll
            for (int i = 0; i < 16; ++i) {
                u32 a16 = (A[i >> 1] >> (16 * (i & 1))) & 0xffffu;
                u32 b16 = (B[i >> 1] >> (16 * (i & 1))) & 0xffffu;
                u32 val = a16 | (b16 << 16);
                int d = dh * 16 + i;
                int cph = (r2v >> 2) ^ (d & 7);
                ((u32*)smem)[(WB + 8192 + d * 64 + cph * 8 + 2 * (r2v & 3)) >> 1] = val;
            }
        }

        const int QB = WB + bb * 2048;
        const int KB = WB + 4096 + bb * 2048;
        f32x4 s[4][4] = {};
        {
            bf16x8 kf[4], qf[4];
#pragma unroll
            for (int mi = 0; mi < 4; ++mi)
                kf[mi] = *(const bf16x8*)&smem[KB + (16 * mi + r15) * 32 + fragsw];
#pragma unroll
            for (int ni = 0; ni < 4; ++ni)
                qf[ni] = *(const bf16x8*)&smem[QB + (16 * ni + r15) * 32 + fragsw];
#pragma unroll
            for (int mi = 0; mi < 4; ++mi)
#pragma unroll
                for (int ni = 0; ni < 4; ++ni)
                    s[mi][ni] = __builtin_amdgcn_mfma_f32_16x16x32_bf16(kf[mi], qf[ni], s[mi][ni], 0, 0, 0);
        }

        float inv4[4];
#pragma unroll
        for (int ni = 0; ni < 4; ++ni) {
            float mx = -1e30f;
#pragma unroll
            for (int mi = 0; mi < 4; ++mi)
#pragma unroll
                for (int jj = 0; jj < 4; ++jj) {
                    float v = s[mi][ni][jj] * SCALE_ATTN;
                    if (mi == 3 && !(g == 0 && jj == 0)) v = -1e30f;
                    s[mi][ni][jj] = v;
                    mx = fmaxf(mx, v);
                }
            mx = fmaxf(mx, __shfl_xor(mx, 16));
            mx = fmaxf(mx, __shfl_xor(mx, 32));
            float sum = 0.f;
#pragma unroll
            for (int mi = 0; mi < 4; ++mi)
#pragma unroll
                for (int jj = 0; jj < 4; ++jj) {
                    float e = __expf(s[mi][ni][jj] - mx);
                    s[mi][ni][jj] = e;
                    sum += e;
                }
            sum += __shfl_xor(sum, 16);
            sum += __shfl_xor(sum, 32);
            inv4[ni] = fast_rcp(sum);
        }

        f32x4 o[4][2] = {};
#pragma unroll
        for (int kh = 0; kh < 2; ++kh) {
#pragma unroll
            for (int m1 = 0; m1 < 2; ++m1) {
                const int mi = 2 * kh + m1;
#pragma unroll
                for (int ni = 0; ni < 4; ++ni)
#pragma unroll
                    for (int jp = 0; jp < 2; ++jp) {
                        float p0 = s[mi][ni][2 * jp] * inv4[ni];
                        float p1 = s[mi][ni][2 * jp + 1] * inv4[ni];
                        u32 val = cvtpk_bf16(p0, p1);
                        int q = 16 * ni + r15;
                        int cph = (2 * m1 + (g >> 1)) ^ (r15 & 3);
                        int off = 4 * (g & 1) + 2 * jp;
                        ((u32*)smem)[(QB + q * 32 + cph * 8 + off) >> 1] = val;
                    }
            }
            bf16x8 pf[4], vf[2];
#pragma unroll
            for (int mi = 0; mi < 4; ++mi)
                pf[mi] = *(const bf16x8*)&smem[QB + (16 * mi + r15) * 32 + fragsw];
#pragma unroll
            for (int ni = 0; ni < 2; ++ni)
                vf[ni] = *(const bf16x8*)&smem[WB + 8192 + (16 * ni + r15) * 64 + ((((4 * kh + g) ^ (r15 & 7))) << 3)];
#pragma unroll
            for (int mi = 0; mi < 4; ++mi)
#pragma unroll
                for (int ni = 0; ni < 2; ++ni)
                    o[mi][ni] = __builtin_amdgcn_mfma_f32_16x16x32_bf16(pf[mi], vf[ni], o[mi][ni], 0, 0, 0);
        }

#pragma unroll
        for (int mi = 0; mi < 4; ++mi)
#pragma unroll
            for (int ni = 0; ni < 2; ++ni)
#pragma unroll
                for (int jj = 0; jj < 4; ++jj) {
                    float ov = o[mi][ni][jj];
                    float op = __shfl_xor(ov, 1);
                    int q = 16 * mi + 4 * g + jj;
                    bool valid = (mi < 3) || (g == 0 && jj == 0);
                    if (((lane & 1) == 0) && valid) {
                        int col = hh * 32 + 16 * ni + r15;
                        int chv = ((col >> 3) ^ ((q >> 2) & 7));
                        ((u32*)smem)[(q * 512 + chv * 8 + (col & 7)) >> 1] = cvtpk_bf16(ov, op);
                    }
                }
    }
#undef ATISSUE

    __syncthreads();
    for (int c = t; c < 3136; c += 256) {
        int r = c >> 6, j = c & 63;
        int chv = j ^ ((r >> 2) & 7);
        uint4 v = *(const uint4*)&smem[r * 512 + chv * 8];
        int gr = base_row + (r / 7) * 56 + r % 7;
        *(uint4*)(aout + (size_t)gr * 512 + j * 8) = v;
    }
}

// ---------------- launch ----------------
extern "C" void kernel_launch(void* const* d_in, const int* in_sizes, int n_in,
                              void* d_out, int out_size, void* d_ws, size_t ws_size,
                              hipStream_t stream) {
    (void)in_sizes; (void)n_in; (void)out_size; (void)ws_size;
    const float* x      = (const float*)d_in[0];
    const float* ln1_g  = (const float*)d_in[1];
    const float* ln1_b  = (const float*)d_in[2];
    const float* qkv_w  = (const float*)d_in[3];
    const float* qkv_b  = (const float*)d_in[4];
    const float* proj_w = (const float*)d_in[5];
    const float* proj_b = (const float*)d_in[6];
    const float* ln2_g  = (const float*)d_in[7];
    const float* ln2_b  = (const float*)d_in[8];
    const float* mlp_w1 = (const float*)d_in[9];
    const float* mlp_b1 = (const float*)d_in[10];
    const float* mlp_w2 = (const float*)d_in[11];
    const float* mlp_b2 = (const float*)d_in[12];
    float* out = (float*)d_out;

    const int M = MROWS;
    char* ws = (char*)d_ws;
    const size_t SZ_H   = (size_t)M * 512 * 2;   // 103MB
    const size_t SZ_BIG = (size_t)M * 2048 * 2;  // 411MB
    u16*   h     = (u16*)ws;
    u16*   x2bf  = (u16*)(ws + SZ_H);            // x2 stored as bf16
    u16*   big   = (u16*)(ws + 2 * SZ_H);
    u16*   qkv_wT  = (u16*)(ws + 2 * SZ_H + SZ_BIG);
    u16*   proj_wT = qkv_wT + 1536 * 512;
    u16*   w1T     = proj_wT + 512 * 512;
    u16*   w2T     = w1T + 2048 * 512;

    transpose_cast<<<(512 * 1536 + 255) / 256, 256, 0, stream>>>(qkv_w, qkv_wT, 512, 1536);
    transpose_cast<<<(512 * 512 + 255) / 256, 256, 0, stream>>>(proj_w, proj_wT, 512, 512);
    transpose_cast<<<(512 * 2048 + 255) / 256, 256, 0, stream>>>(mlp_w1, w1T, 512, 2048);
    transpose_cast<<<(2048 * 512 + 255) / 256, 256, 0, stream>>>(mlp_w2, w2T, 2048, 512);

    ln_kernel<<<M / 4, 256, 0, stream>>>(x, ln1_g, ln1_b, h);

    // K=512 GEMMs: BK=32 / 4 blocks/CU
    gemm_bt32<EPI_BF16><<<(M / BM) * (1536 / BN), 256, 0, stream>>>(h, qkv_wT, qkv_b, nullptr, big, M, 1536, 512, 1536 / BN);

    attn_kernel<<<2048, 256, 0, stream>>>(big, h);

    // proj: x2 = attn@W + b + x, stored bf16
    gemm_bt32<EPI_RES_BF16><<<(M / BM) * (512 / BN), 256, 0, stream>>>(h, proj_wT, proj_b, x, x2bf, M, 512, 512, 512 / BN);

    ln_kernel_bf16<<<M / 4, 256, 0, stream>>>(x2bf, ln2_g, ln2_b, h);

    gemm_bt32<EPI_GELU_BF16><<<(M / BM) * (2048 / BN), 256, 0, stream>>>(h, w1T, mlp_b1, nullptr, big, M, 2048, 512, 2048 / BN);

    // mlp2: out(fp32) = mid@W2 + b2 + x2(bf16)
    gemm_bt64<EPI_RESBF_F32><<<(M / BM) * (512 / BN), 256, 0, stream>>>(big, w2T, mlp_b2, x2bf, out, M, 512, 2048, 512 / BN);
}

// Round 17
// 1133.885 us; speedup vs baseline: 1.0413x; 1.0146x over previous
//
#include <hip/hip_runtime.h>
#include <hip/hip_bf16.h>
#include <math.h>

typedef unsigned short u16;
typedef unsigned int u32;
typedef __bf16 bf16x8 __attribute__((ext_vector_type(8)));
typedef float f32x4 __attribute__((ext_vector_type(4)));

#define MROWS 100352   // 32 * 56 * 56
#define CDIM 512
#define SCALE_ATTN 0.17677669529663687f

__device__ __forceinline__ u16 f2bf(float f) {
    u32 u = __float_as_uint(f);
    u32 r = (u + 0x7fffu + ((u >> 16) & 1u)) >> 16;   // RNE
    return (u16)r;
}

__device__ __forceinline__ u32 cvtpk_bf16(float lo, float hi) {
    u32 r;
    asm volatile("v_cvt_pk_bf16_f32 %0, %1, %2" : "=v"(r) : "v"(lo), "v"(hi));
    return r;
}
__device__ __forceinline__ float fast_rcp(float x) {
    float r;
    asm volatile("v_rcp_f32 %0, %1" : "=v"(r) : "v"(x));
    return r;
}
__device__ __forceinline__ float fast_rsq(float x) {
    float r;
    asm volatile("v_rsq_f32 %0, %1" : "=v"(r) : "v"(x));
    return r;
}

// ---------------- merged transpose + cast: all 4 weights in one launch ----------------
// qkv_w (512x1536) -> [786432), proj_w (512x512) -> [262144), mlp_w1 (512x2048), mlp_w2 (2048x512)
__global__ void transpose_cast_all(const float* __restrict__ w0, const float* __restrict__ w1,
                                   const float* __restrict__ w2, const float* __restrict__ w3,
                                   u16* __restrict__ o0, u16* __restrict__ o1,
                                   u16* __restrict__ o2, u16* __restrict__ o3) {
    int idx = blockIdx.x * 256 + threadIdx.x;
    if (idx < 786432) {
        int k = idx / 1536, n = idx % 1536;
        o0[(size_t)n * 512 + k] = f2bf(w0[idx]);
    } else if (idx < 786432 + 262144) {
        int i = idx - 786432;
        int k = i >> 9, n = i & 511;
        o1[(size_t)n * 512 + k] = f2bf(w1[i]);
    } else if (idx < 786432 + 262144 + 1048576) {
        int i = idx - (786432 + 262144);
        int k = i >> 11, n = i & 2047;
        o2[(size_t)n * 512 + k] = f2bf(w2[i]);
    } else {
        int i = idx - (786432 + 262144 + 1048576);
        int k = i >> 9, n = i & 511;
        o3[(size_t)n * 2048 + k] = f2bf(w3[i]);
    }
}

// ---------------- LayerNorm fp32-in -> bf16, one wave per row (C=512) ----------------
__global__ __launch_bounds__(256) void ln_kernel(const float* __restrict__ x, const float* __restrict__ g,
                                                 const float* __restrict__ bta, u16* __restrict__ out) {
    int row = blockIdx.x * 4 + (threadIdx.x >> 6);
    int lane = threadIdx.x & 63;
    const float* xr = x + (size_t)row * CDIM + lane * 8;
    float4 v0 = *(const float4*)xr;
    float4 v1 = *(const float4*)(xr + 4);
    float xv[8] = {v0.x, v0.y, v0.z, v0.w, v1.x, v1.y, v1.z, v1.w};
    float s = 0.f, ss = 0.f;
#pragma unroll
    for (int i = 0; i < 8; ++i) { s += xv[i]; ss += xv[i] * xv[i]; }
#pragma unroll
    for (int o = 1; o < 64; o <<= 1) { s += __shfl_xor(s, o); ss += __shfl_xor(ss, o); }
    float mu = s * (1.f / CDIM);
    float var = ss * (1.f / CDIM) - mu * mu;
    float rs = fast_rsq(var + 1e-6f);
    int c = lane * 8;
    float y[8];
#pragma unroll
    for (int i = 0; i < 8; ++i)
        y[i] = (xv[i] - mu) * rs * g[c + i] + bta[c + i];
    uint4 ov;
    ov.x = cvtpk_bf16(y[0], y[1]);
    ov.y = cvtpk_bf16(y[2], y[3]);
    ov.z = cvtpk_bf16(y[4], y[5]);
    ov.w = cvtpk_bf16(y[6], y[7]);
    *(uint4*)(out + (size_t)row * CDIM + c) = ov;
}

// ---------------- LayerNorm bf16-in -> bf16 (for x2 stored as bf16) ----------------
__global__ __launch_bounds__(256) void ln_kernel_bf16(const u16* __restrict__ x, const float* __restrict__ g,
                                                      const float* __restrict__ bta, u16* __restrict__ out) {
    int row = blockIdx.x * 4 + (threadIdx.x >> 6);
    int lane = threadIdx.x & 63;
    const u16* xr = x + (size_t)row * CDIM + lane * 8;
    uint4 v = *(const uint4*)xr;
    float xv[8];
    xv[0] = __uint_as_float(v.x << 16); xv[1] = __uint_as_float(v.x & 0xffff0000u);
    xv[2] = __uint_as_float(v.y << 16); xv[3] = __uint_as_float(v.y & 0xffff0000u);
    xv[4] = __uint_as_float(v.z << 16); xv[5] = __uint_as_float(v.z & 0xffff0000u);
    xv[6] = __uint_as_float(v.w << 16); xv[7] = __uint_as_float(v.w & 0xffff0000u);
    float s = 0.f, ss = 0.f;
#pragma unroll
    for (int i = 0; i < 8; ++i) { s += xv[i]; ss += xv[i] * xv[i]; }
#pragma unroll
    for (int o = 1; o < 64; o <<= 1) { s += __shfl_xor(s, o); ss += __shfl_xor(ss, o); }
    float mu = s * (1.f / CDIM);
    float var = ss * (1.f / CDIM) - mu * mu;
    float rs = fast_rsq(var + 1e-6f);
    int c = lane * 8;
    float y[8];
#pragma unroll
    for (int i = 0; i < 8; ++i)
        y[i] = (xv[i] - mu) * rs * g[c + i] + bta[c + i];
    uint4 ov;
    ov.x = cvtpk_bf16(y[0], y[1]);
    ov.y = cvtpk_bf16(y[2], y[3]);
    ov.z = cvtpk_bf16(y[4], y[5]);
    ov.w = cvtpk_bf16(y[6], y[7]);
    *(uint4*)(out + (size_t)row * CDIM + c) = ov;
}

#define BM 128
#define BN 128

enum { EPI_BF16 = 0, EPI_GELU_BF16 = 1, EPI_RES_BF16 = 2, EPI_RESBF_F32 = 3 };

__device__ __forceinline__ void gload_lds16(const void* g, void* l) {
    __builtin_amdgcn_global_load_lds(
        (const __attribute__((address_space(1))) u32*)g,
        (__attribute__((address_space(3))) u32*)l, 16, 0, 0);
}

#define WAITVM4() asm volatile("s_waitcnt vmcnt(4)" ::: "memory")
#define WAITVM8() asm volatile("s_waitcnt vmcnt(8)" ::: "memory")
#define WAITVM12() asm volatile("s_waitcnt vmcnt(12)" ::: "memory")
#define WAITVM0() asm volatile("s_waitcnt vmcnt(0)" ::: "memory")
#define BARRIER() __builtin_amdgcn_s_barrier()
#define SCHEDBAR() __builtin_amdgcn_sched_barrier(0)

__device__ __forceinline__ float gelu_tanh(float x) {
    float y = x * fmaf(x * x, 0.0356774081f, 0.7978845608f);
    y = fmaxf(y, -15.f);
    float u = __expf(-2.f * y);
    float th = (1.f - u) * fast_rcp(1.f + u);
    return 0.5f * x * (1.f + th);
}

// ---------------- common epilogue (coalesced via per-wave LDS staging) ----------------
// bf16 outs: 2 passes x (32B ep read + 16B uint4 store). fp32 out: 4 passes x float4.
template <int EPI>
__device__ __forceinline__ void gemm_epilogue(f32x4 (&acc)[4][4], u16* smem,
                                              const float* __restrict__ bias, const void* __restrict__ res,
                                              void* __restrict__ outp, int N,
                                              int m0, int n0, int w, int lane) {
    const int r15 = lane & 15;
    float* ep = (float*)smem + w * (16 * 76);
    const int lg = lane >> 4;
#pragma unroll
    for (int mi = 0; mi < 4; ++mi) {
#pragma unroll
        for (int ni = 0; ni < 4; ++ni)
#pragma unroll
            for (int j = 0; j < 4; ++j)
                ep[(lg * 4 + j) * 76 + ni * 16 + r15] = acc[mi][ni][j];
        if (EPI == EPI_RESBF_F32) {
#pragma unroll
            for (int p = 0; p < 4; ++p) {
                int lr = p * 4 + lg;
                f32x4 v = *(f32x4*)&ep[lr * 76 + r15 * 4];
                int grow = m0 + (w >> 1) * 64 + mi * 16 + lr;
                int gcol = n0 + (w & 1) * 64 + r15 * 4;
                float4 bv = *(const float4*)&bias[gcol];
                float o0 = v[0] + bv.x, o1 = v[1] + bv.y, o2 = v[2] + bv.z, o3 = v[3] + bv.w;
                size_t off = (size_t)grow * N + gcol;
                uint2 rb = *(const uint2*)((const u16*)res + off);
                o0 += __uint_as_float(rb.x << 16);
                o1 += __uint_as_float(rb.x & 0xffff0000u);
                o2 += __uint_as_float(rb.y << 16);
                o3 += __uint_as_float(rb.y & 0xffff0000u);
                *(float4*)((float*)outp + off) = make_float4(o0, o1, o2, o3);
            }
        } else {
#pragma unroll
            for (int pass = 0; pass < 2; ++pass) {
                int lr = pass * 8 + (lane >> 3);
                int c8 = (lane & 7) * 8;
                f32x4 v0 = *(f32x4*)&ep[lr * 76 + c8];
                f32x4 v1 = *(f32x4*)&ep[lr * 76 + c8 + 4];
                int grow = m0 + (w >> 1) * 64 + mi * 16 + lr;
                int gcol = n0 + (w & 1) * 64 + c8;
                float4 bv0 = *(const float4*)&bias[gcol];
                float4 bv1 = *(const float4*)&bias[gcol + 4];
                float o[8] = {v0[0] + bv0.x, v0[1] + bv0.y, v0[2] + bv0.z, v0[3] + bv0.w,
                              v1[0] + bv1.x, v1[1] + bv1.y, v1[2] + bv1.z, v1[3] + bv1.w};
                size_t off = (size_t)grow * N + gcol;
                if (EPI == EPI_GELU_BF16) {
#pragma unroll
                    for (int i = 0; i < 8; ++i) o[i] = gelu_tanh(o[i]);
                }
                if (EPI == EPI_RES_BF16) {
                    float4 r0 = *(const float4*)((const float*)res + off);
                    float4 r1 = *(const float4*)((const float*)res + off + 4);
                    o[0] += r0.x; o[1] += r0.y; o[2] += r0.z; o[3] += r0.w;
                    o[4] += r1.x; o[5] += r1.y; o[6] += r1.z; o[7] += r1.w;
                }
                uint4 ov;
                ov.x = cvtpk_bf16(o[0], o[1]);
                ov.y = cvtpk_bf16(o[2], o[3]);
                ov.z = cvtpk_bf16(o[4], o[5]);
                ov.w = cvtpk_bf16(o[6], o[7]);
                *(uint4*)((u16*)outp + off) = ov;
            }
        }
    }
}

// ---------------- GEMM variant A: BK=32, 4 blocks/CU — for K=512 ----------------
#define BK32 32
#define BUFE32 (BM * BK32 + BN * BK32)   // 8192 u16 = 16KB

template <int EPI>
__global__ __launch_bounds__(256, 4) void gemm_bt32(const u16* __restrict__ A, const u16* __restrict__ BT,
                                                    const float* __restrict__ bias, const void* __restrict__ res,
                                                    void* __restrict__ outp, int M, int N, int K, int nnb) {
    __shared__ __align__(16) u16 smem[2 * BUFE32];   // 32 KB

    const int t = threadIdx.x;
    const int lane = t & 63;
    const int w = t >> 6;
    const int wr = w >> 1, wc = w & 1;

    const int nwg = gridDim.x;
    const int chunk = nwg >> 3;
    const int wg = (blockIdx.x & 7) * chunk + (blockIdx.x >> 3);
    const int m0 = (wg / nnb) * BM;
    const int n0 = (wg % nnb) * BN;

    f32x4 acc[4][4] = {};

    const int r15 = lane & 15;
    const int rc8 = (((lane >> 4) ^ ((r15 & 3) ^ ((r15 >> 2) & 3))) << 3);

    const int srow = t >> 2;                                        // 0..63
    const int scol = (((t & 3) ^ ((srow & 3) ^ ((srow >> 2) & 3))) << 3);
    const u16* Ag = A + (size_t)(m0 + srow) * K + scol;
    const u16* Bg = BT + (size_t)(n0 + srow) * K + scol;

    const int nt = K / BK32;

#define ISSUE32(buf_, tile_)                                                         \
    {                                                                                \
        u16* dst_ = smem + (buf_) * BUFE32;                                          \
        const int kt_ = (tile_) * BK32;                                              \
        _Pragma("unroll")                                                            \
        for (int i = 0; i < 2; ++i)                                                  \
            gload_lds16(Ag + (size_t)(i * 64) * K + kt_, &dst_[i * 2048 + t * 8]);   \
        _Pragma("unroll")                                                            \
        for (int i = 0; i < 2; ++i)                                                  \
            gload_lds16(Bg + (size_t)(i * 64) * K + kt_, &dst_[4096 + i * 2048 + t * 8]); \
    }

    ISSUE32(0, 0);
    ISSUE32(1, 1);

    for (int tt = 0; tt < nt; ++tt) {
        const int d = tt & 1;

        if (tt + 1 < nt) WAITVM4(); else WAITVM0();
        BARRIER();
        SCHEDBAR();

        const u16* As = smem + d * BUFE32;
        const u16* Bs = As + BM * BK32;
        bf16x8 af[4], bf[4];
#pragma unroll
        for (int mi = 0; mi < 4; ++mi)
            af[mi] = *(const bf16x8*)&As[(wr * 64 + mi * 16 + r15) * BK32 + rc8];
#pragma unroll
        for (int ni = 0; ni < 4; ++ni)
            bf[ni] = *(const bf16x8*)&Bs[(wc * 64 + ni * 16 + r15) * BK32 + rc8];
#pragma unroll
        for (int mi = 0; mi < 4; ++mi)
#pragma unroll
            for (int ni = 0; ni < 4; ++ni)
                acc[mi][ni] = __builtin_amdgcn_mfma_f32_16x16x32_bf16(af[mi], bf[ni], acc[mi][ni], 0, 0, 0);

        SCHEDBAR();
        BARRIER();
        if (tt + 2 < nt) ISSUE32(d, tt + 2);
    }
#undef ISSUE32

    gemm_epilogue<EPI>(acc, smem, bias, res, outp, N, m0, n0, w, lane);
}

// ---------------- GEMM variant B: BK=64, 2 blocks/CU — for K=2048 ----------------
#define BK64 64
#define BUFE64 (BM * BK64 + BN * BK64)   // 16384 u16 = 32KB

template <int EPI>
__global__ __launch_bounds__(256, 2) void gemm_bt64(const u16* __restrict__ A, const u16* __restrict__ BT,
                                                    const float* __restrict__ bias, const void* __restrict__ res,
                                                    void* __restrict__ outp, int M, int N, int K, int nnb) {
    __shared__ __align__(16) u16 smem[2 * BUFE64];   // 64 KB

    const int t = threadIdx.x;
    const int lane = t & 63;
    const int w = t >> 6;
    const int wr = w >> 1, wc = w & 1;

    const int nwg = gridDim.x;
    const int chunk = nwg >> 3;
    const int wg = (blockIdx.x & 7) * chunk + (blockIdx.x >> 3);
    const int m0 = (wg / nnb) * BM;
    const int n0 = (wg % nnb) * BN;

    f32x4 acc[4][4] = {};

    const int r15 = lane & 15;
    const int khalf = (lane >> 4) << 3;
    const int xorv = (r15 & 7) << 3;

    const int srow = t >> 3;
    const int scol = (((t & 7) ^ (srow & 7)) << 3);
    const u16* Ag = A + (size_t)(m0 + srow) * K + scol;
    const u16* Bg = BT + (size_t)(n0 + srow) * K + scol;

    const int nt = K / BK64;

#define ISSUE64(buf_, tile_)                                                         \
    {                                                                                \
        u16* dst_ = smem + (buf_) * BUFE64;                                          \
        const int kt_ = (tile_) * BK64;                                              \
        _Pragma("unroll")                                                            \
        for (int i = 0; i < 4; ++i)                                                  \
            gload_lds16(Ag + (size_t)(i * 32) * K + kt_, &dst_[i * 2048 + t * 8]);   \
        _Pragma("unroll")                                                            \
        for (int i = 0; i < 4; ++i)                                                  \
            gload_lds16(Bg + (size_t)(i * 32) * K + kt_, &dst_[8192 + i * 2048 + t * 8]); \
    }

    ISSUE64(0, 0);
    ISSUE64(1, 1);

    for (int tt = 0; tt < nt; ++tt) {
        const int d = tt & 1;

        if (tt + 1 < nt) WAITVM8(); else WAITVM0();
        BARRIER();
        SCHEDBAR();

        const u16* As = smem + d * BUFE64;
        const u16* Bs = As + BM * BK64;
        bf16x8 af[4][2], bf[4][2];
#pragma unroll
        for (int mi = 0; mi < 4; ++mi)
#pragma unroll
            for (int kk = 0; kk < 2; ++kk)
                af[mi][kk] = *(const bf16x8*)&As[(wr * 64 + mi * 16 + r15) * BK64 + ((kk * 32 + khalf) ^ xorv)];
#pragma unroll
        for (int ni = 0; ni < 4; ++ni)
#pragma unroll
            for (int kk = 0; kk < 2; ++kk)
                bf[ni][kk] = *(const bf16x8*)&Bs[(wc * 64 + ni * 16 + r15) * BK64 + ((kk * 32 + khalf) ^ xorv)];
#pragma unroll
        for (int kk = 0; kk < 2; ++kk)
#pragma unroll
            for (int mi = 0; mi < 4; ++mi)
#pragma unroll
                for (int ni = 0; ni < 4; ++ni)
                    acc[mi][ni] = __builtin_amdgcn_mfma_f32_16x16x32_bf16(af[mi][kk], bf[ni][kk], acc[mi][ni], 0, 0, 0);

        SCHEDBAR();
        BARRIER();
        if (tt + 2 < nt) ISSUE64(d, tt + 2);
    }
#undef ISSUE64

    gemm_epilogue<EPI>(acc, smem, bias, res, outp, N, m0, n0, w, lane);
}

// ---------------- windowed attention v3: MFMA, one block per window ----------------
__global__ __launch_bounds__(256) void attn_kernel(const u16* __restrict__ qkv, u16* __restrict__ aout) {
    __shared__ __align__(16) u16 smem[73728];   // 144 KB

    const int t = threadIdx.x;
    const int lane = t & 63;
    const int w = t >> 6;
    const int g = lane >> 4;
    const int r15 = lane & 15;
    const int wdw = blockIdx.x;
    const int b = wdw >> 6, wy = (wdw >> 3) & 7, wx = wdw & 7;
    const int base_row = b * 3136 + wy * 7 * 56 + wx * 7;

    const int WB = 32768 + w * 10240;

    const int sg_row = lane >> 2;
    const int sg_c = (lane & 3) ^ (sg_row & 3);
    int grq[4];
#pragma unroll
    for (int u = 0; u < 4; ++u) {
        int rr = u * 16 + sg_row; rr = rr > 48 ? 48 : rr;
        grq[u] = base_row + (rr / 7) * 56 + rr % 7;
    }
    const int r2v = lane & 31;
    const int dh = lane >> 5;
    int k0 = 2 * r2v, k1 = 2 * r2v + 1;
    k0 = k0 > 48 ? 48 : k0; k1 = k1 > 48 ? 48 : k1;
    const int grv0 = base_row + (k0 / 7) * 56 + k0 % 7;
    const int grv1 = base_row + (k1 / 7) * 56 + k1 % 7;

    const int fragsw = ((g ^ (r15 & 3)) << 3);

#define ATISSUE(rr_, bb_, va0_, va1_, vb0_, vb1_)                                    \
    {                                                                                \
        const int hh_ = w * 4 + (rr_);                                               \
        _Pragma("unroll")                                                            \
        for (int u = 0; u < 4; ++u)                                                  \
            gload_lds16(qkv + (size_t)grq[u] * 1536 + hh_ * 32 + sg_c * 8,           \
                        &smem[WB + (bb_) * 2048 + u * 512 + lane * 8]);              \
        _Pragma("unroll")                                                            \
        for (int u = 0; u < 4; ++u)                                                  \
            gload_lds16(qkv + (size_t)grq[u] * 1536 + 512 + hh_ * 32 + sg_c * 8,     \
                        &smem[WB + 4096 + (bb_) * 2048 + u * 512 + lane * 8]);       \
        const u16* vs0_ = qkv + (size_t)grv0 * 1536 + 1024 + hh_ * 32 + dh * 16;     \
        const u16* vs1_ = qkv + (size_t)grv1 * 1536 + 1024 + hh_ * 32 + dh * 16;     \
        va0_ = *(const uint4*)vs0_; va1_ = *(const uint4*)(vs0_ + 8);                \
        vb0_ = *(const uint4*)vs1_; vb1_ = *(const uint4*)(vs1_ + 8);                \
    }

    uint4 va0[2], va1[2], vb0[2], vb1[2];
    ATISSUE(0, 0, va0[0], va1[0], vb0[0], vb1[0]);

#pragma unroll
    for (int r = 0; r < 4; ++r) {
        const int bb = r & 1;
        const int hh = w * 4 + r;
        if (r < 3) ATISSUE(r + 1, bb ^ 1, va0[(r + 1) & 1], va1[(r + 1) & 1], vb0[(r + 1) & 1], vb1[(r + 1) & 1]);
        if (r < 3) WAITVM12(); else WAITVM0();
        SCHEDBAR();

        {
            u32 A[8], B[8];
            A[0] = va0[bb].x; A[1] = va0[bb].y; A[2] = va0[bb].z; A[3] = va0[bb].w;
            A[4] = va1[bb].x; A[5] = va1[bb].y; A[6] = va1[bb].z; A[7] = va1[bb].w;
            B[0] = vb0[bb].x; B[1] = vb0[bb].y; B[2] = vb0[bb].z; B[3] = vb0[bb].w;
            B[4] = vb1[bb].x; B[5] = vb1[bb].y; B[6] = vb1[bb].z; B[7] = vb1[bb].w;
#pragma unroll
            for (int i = 0; i < 16; ++i) {
                u32 a16 = (A[i >> 1] >> (16 * (i & 1))) & 0xffffu;
                u32 b16 = (B[i >> 1] >> (16 * (i & 1))) & 0xffffu;
                u32 val = a16 | (b16 << 16);
                int d = dh * 16 + i;
                int cph = (r2v >> 2) ^ (d & 7);
                ((u32*)smem)[(WB + 8192 + d * 64 + cph * 8 + 2 * (r2v & 3)) >> 1] = val;
            }
        }

        const int QB = WB + bb * 2048;
        const int KB = WB + 4096 + bb * 2048;
        f32x4 s[4][4] = {};
        {
            bf16x8 kf[4], qf[4];
#pragma unroll
            for (int mi = 0; mi < 4; ++mi)
                kf[mi] = *(const bf16x8*)&smem[KB + (16 * mi + r15) * 32 + fragsw];
#pragma unroll
            for (int ni = 0; ni < 4; ++ni)
                qf[ni] = *(const bf16x8*)&smem[QB + (16 * ni + r15) * 32 + fragsw];
#pragma unroll
            for (int mi = 0; mi < 4; ++mi)
#pragma unroll
                for (int ni = 0; ni < 4; ++ni)
                    s[mi][ni] = __builtin_amdgcn_mfma_f32_16x16x32_bf16(kf[mi], qf[ni], s[mi][ni], 0, 0, 0);
        }

        float inv4[4];
#pragma unroll
        for (int ni = 0; ni < 4; ++ni) {
            float mx = -1e30f;
#pragma unroll
            for (int mi = 0; mi < 4; ++mi)
#pragma unroll
                for (int jj = 0; jj < 4; ++jj) {
                    float v = s[mi][ni][jj] * SCALE_ATTN;
                    if (mi == 3 && !(g == 0 && jj == 0)) v = -1e30f;
                    s[mi][ni][jj] = v;
                    mx = fmaxf(mx, v);
                }
            mx = fmaxf(mx, __shfl_xor(mx, 16));
            mx = fmaxf(mx, __shfl_xor(mx, 32));
            float sum = 0.f;
#pragma unroll
            for (int mi = 0; mi < 4; ++mi)
#pragma unroll
                for (int jj = 0; jj < 4; ++jj) {
                    float e = __expf(s[mi][ni][jj] - mx);
                    s[mi][ni][jj] = e;
                    sum += e;
                }
            sum += __shfl_xor(sum, 16);
            sum += __shfl_xor(sum, 32);
            inv4[ni] = fast_rcp(sum);
        }

        f32x4 o[4][2] = {};
#pragma unroll
        for (int kh = 0; kh < 2; ++kh) {
#pragma unroll
            for (int m1 = 0; m1 < 2; ++m1) {
                const int mi = 2 * kh + m1;
#pragma unroll
                for (int ni = 0; ni < 4; ++ni)
#pragma unroll
                    for (int jp = 0; jp < 2; ++jp) {
                        float p0 = s[mi][ni][2 * jp] * inv4[ni];
                        float p1 = s[mi][ni][2 * jp + 1] * inv4[ni];
                        u32 val = cvtpk_bf16(p0, p1);
                        int q = 16 * ni + r15;
                        int cph = (2 * m1 + (g >> 1)) ^ (r15 & 3);
                        int off = 4 * (g & 1) + 2 * jp;
                        ((u32*)smem)[(QB + q * 32 + cph * 8 + off) >> 1] = val;
                    }
            }
            bf16x8 pf[4], vf[2];
#pragma unroll
            for (int mi = 0; mi < 4; ++mi)
                pf[mi] = *(const bf16x8*)&smem[QB + (16 * mi + r15) * 32 + fragsw];
#pragma unroll
            for (int ni = 0; ni < 2; ++ni)
                vf[ni] = *(const bf16x8*)&smem[WB + 8192 + (16 * ni + r15) * 64 + ((((4 * kh + g) ^ (r15 & 7))) << 3)];
#pragma unroll
            for (int mi = 0; mi < 4; ++mi)
#pragma unroll
                for (int ni = 0; ni < 2; ++ni)
                    o[mi][ni] = __builtin_amdgcn_mfma_f32_16x16x32_bf16(pf[mi], vf[ni], o[mi][ni], 0, 0, 0);
        }

#pragma unroll
        for (int mi = 0; mi < 4; ++mi)
#pragma unroll
            for (int ni = 0; ni < 2; ++ni)
#pragma unroll
                for (int jj = 0; jj < 4; ++jj) {
                    float ov = o[mi][ni][jj];
                    float op = __shfl_xor(ov, 1);
                    int q = 16 * mi + 4 * g + jj;
                    bool valid = (mi < 3) || (g == 0 && jj == 0);
                    if (((lane & 1) == 0) && valid) {
                        int col = hh * 32 + 16 * ni + r15;
                        int chv = ((col >> 3) ^ ((q >> 2) & 7));
                        ((u32*)smem)[(q * 512 + chv * 8 + (col & 7)) >> 1] = cvtpk_bf16(ov, op);
                    }
                }
    }
#undef ATISSUE

    __syncthreads();
    for (int c = t; c < 3136; c += 256) {
        int r = c >> 6, j = c & 63;
        int chv = j ^ ((r >> 2) & 7);
        uint4 v = *(const uint4*)&smem[r * 512 + chv * 8];
        int gr = base_row + (r / 7) * 56 + r % 7;
        *(uint4*)(aout + (size_t)gr * 512 + j * 8) = v;
    }
}

// ---------------- launch ----------------
extern "C" void kernel_launch(void* const* d_in, const int* in_sizes, int n_in,
                              void* d_out, int out_size, void* d_ws, size_t ws_size,
                              hipStream_t stream) {
    (void)in_sizes; (void)n_in; (void)out_size; (void)ws_size;
    const float* x      = (const float*)d_in[0];
    const float* ln1_g  = (const float*)d_in[1];
    const float* ln1_b  = (const float*)d_in[2];
    const float* qkv_w  = (const float*)d_in[3];
    const float* qkv_b  = (const float*)d_in[4];
    const float* proj_w = (const float*)d_in[5];
    const float* proj_b = (const float*)d_in[6];
    const float* ln2_g  = (const float*)d_in[7];
    const float* ln2_b  = (const float*)d_in[8];
    const float* mlp_w1 = (const float*)d_in[9];
    const float* mlp_b1 = (const float*)d_in[10];
    const float* mlp_w2 = (const float*)d_in[11];
    const float* mlp_b2 = (const float*)d_in[12];
    float* out = (float*)d_out;

    const int M = MROWS;
    char* ws = (char*)d_ws;
    const size_t SZ_H   = (size_t)M * 512 * 2;   // 103MB
    const size_t SZ_BIG = (size_t)M * 2048 * 2;  // 411MB
    u16*   h     = (u16*)ws;
    u16*   x2bf  = (u16*)(ws + SZ_H);            // x2 stored as bf16
    u16*   big   = (u16*)(ws + 2 * SZ_H);
    u16*   qkv_wT  = (u16*)(ws + 2 * SZ_H + SZ_BIG);
    u16*   proj_wT = qkv_wT + 1536 * 512;
    u16*   w1T     = proj_wT + 512 * 512;
    u16*   w2T     = w1T + 2048 * 512;

    // all 4 weight transposes in one launch (3145728 elems)
    transpose_cast_all<<<3145728 / 256, 256, 0, stream>>>(qkv_w, proj_w, mlp_w1, mlp_w2,
                                                          qkv_wT, proj_wT, w1T, w2T);

    ln_kernel<<<M / 4, 256, 0, stream>>>(x, ln1_g, ln1_b, h);

    // K=512 GEMMs: BK=32 / 4 blocks/CU
    gemm_bt32<EPI_BF16><<<(M / BM) * (1536 / BN), 256, 0, stream>>>(h, qkv_wT, qkv_b, nullptr, big, M, 1536, 512, 1536 / BN);

    attn_kernel<<<2048, 256, 0, stream>>>(big, h);

    // proj: x2 = attn@W + b + x, stored bf16
    gemm_bt32<EPI_RES_BF16><<<(M / BM) * (512 / BN), 256, 0, stream>>>(h, proj_wT, proj_b, x, x2bf, M, 512, 512, 512 / BN);

    ln_kernel_bf16<<<M / 4, 256, 0, stream>>>(x2bf, ln2_g, ln2_b, h);

    gemm_bt32<EPI_GELU_BF16><<<(M / BM) * (2048 / BN), 256, 0, stream>>>(h, w1T, mlp_b1, nullptr, big, M, 2048, 512, 2048 / BN);

    // mlp2: out(fp32) = mid@W2 + b2 + x2(bf16)
    gemm_bt64<EPI_RESBF_F32><<<(M / BM) * (512 / BN), 256, 0, stream>>>(big, w2T, mlp_b2, x2bf, out, M, 512, 2048, 512 / BN);
}